// Round 10
// baseline (70.523 us; speedup 1.0000x reference)
//
#include <hip/hip_runtime.h>

// LNCC loss: I,J [16,1,768,768] f32 -> out [16] f32
// R10: colsum-sharing design. Each thread owns 4 cols; 5-channel running
// vertical colsums live in registers (no halo redundancy, no ring). Per row
// the 9-row colsums are published to a double-buffered one-row LDS strip;
// after one barrier each thread reads only its L/R neighbor float4s per
// channel for the horizontal 9-sum. Out-row is re-read from global (L2/L3
// warm). 31KB LDS -> 4 blocks/CU = 12 waves/CU (2x R9's TLP), 1024 blocks
// exactly fill the GPU (no tail).

constexpr int BATCH = 16;
constexpr int H = 768;
constexpr int W = 768;
constexpr float INV_WS = 1.0f / 81.0f;
constexpr float EPS = 3.0590232050182579e-07f;   // exp(-15)

constexpr int SEG = 12;                   // output rows per block
constexpr int NSEG = H / SEG;             // 64
constexpr int NTHREADS = 192;             // 3 waves; 192*4 = 768 cols
constexpr int LWC = 4 + W + 4;            // 776 floats per channel strip

__global__ void zero_acc_kernel(float* acc) {
    if (threadIdx.x < BATCH) acc[threadIdx.x] = 0.0f;
}

// float4 componentwise helpers (explicit, fma-based)
#define F4SCALE(a, s)  { a.x *= (s); a.y *= (s); a.z *= (s); a.w *= (s); }
#define F4ADD(a, u)    { a.x += u.x; a.y += u.y; a.z += u.z; a.w += u.w; }
#define F4SUB(a, u)    { a.x -= u.x; a.y -= u.y; a.z -= u.z; a.w -= u.w; }
#define F4FMA(a, u, v) { a.x = fmaf(u.x, v.x, a.x); a.y = fmaf(u.y, v.y, a.y); \
                         a.z = fmaf(u.z, v.z, a.z); a.w = fmaf(u.w, v.w, a.w); }
#define F4FMS(a, u, v) { a.x = fmaf(u.x, -v.x, a.x); a.y = fmaf(u.y, -v.y, a.y); \
                         a.z = fmaf(u.z, -v.z, a.z); a.w = fmaf(u.w, -v.w, a.w); }

__launch_bounds__(NTHREADS, 3)
__global__ void lncc_cs(const float* __restrict__ gI, const float* __restrict__ gJ,
                        float* __restrict__ acc)
{
    __shared__ float csb[2][5][LWC];      // 2*5*776*4 = 31040 B

    const int t    = threadIdx.x;
    const int lane = t & 63;
    const int r0   = blockIdx.x * SEG;
    const int b    = blockIdx.y;
    const int gc   = 4 * t;               // first owned global col

    const float* __restrict__ Ib = gI + (size_t)b * (H * W);
    const float* __restrict__ Jb = gJ + (size_t)b * (H * W);

    // zero the 4-col edge pads of all (buf,channel) strips once
    if (t < 20) {
        const int bu = t / 10, ch = (t % 10) >> 1, side = t & 1;
        *(float4*)&csb[bu][ch][side ? (LWC - 4) : 0] = make_float4(0.f, 0.f, 0.f, 0.f);
    }

    // running 8-row colsums of the 5 channels for the 4 owned cols
    float4 cs0 = {0,0,0,0}, cs1 = {0,0,0,0}, cs2 = {0,0,0,0},
           cs3 = {0,0,0,0}, cs4 = {0,0,0,0};

    // ---- warm-up: in-add rows r0-4 .. r0+3 (zero above the image) ----
    #pragma unroll
    for (int k = 0; k < 8; ++k) {
        const int rr = r0 - 4 + k;                 // <= 759, never >= H
        const int rc = max(rr, 0);
        const float rm = (rr >= 0) ? 1.0f : 0.0f;
        float4 vi = *(const float4*)(Ib + (size_t)rc * W + gc);
        float4 vj = *(const float4*)(Jb + (size_t)rc * W + gc);
        F4SCALE(vi, rm) F4SCALE(vj, rm)
        F4ADD(cs0, vi) F4ADD(cs1, vj)
        F4FMA(cs2, vi, vi) F4FMA(cs3, vj, vj) F4FMA(cs4, vi, vj)
    }

    // prefetch P: in-row r0+4, out-row r0-4 (clamped; masked at consume)
    float4 Pii, Pij, Poi, Poj;
    {
        const int ri = min(r0 + 4, H - 1);
        const int ro = max(r0 - 4, 0);
        Pii = *(const float4*)(Ib + (size_t)ri * W + gc);
        Pij = *(const float4*)(Jb + (size_t)ri * W + gc);
        Poi = *(const float4*)(Ib + (size_t)ro * W + gc);
        Poj = *(const float4*)(Jb + (size_t)ro * W + gc);
    }

    float accum = 0.0f;

    // ---- main loop: one output row per iteration, one barrier per row ----
    #pragma unroll 1
    for (int r = r0; r < r0 + SEG; ++r) {
        // prefetch Q for row r+1 (flies under this row's compute)
        float4 Qii, Qij, Qoi, Qoj;
        {
            const int ri = min(r + 5, H - 1);
            const int ro = max(r - 3, 0);
            Qii = *(const float4*)(Ib + (size_t)ri * W + gc);
            Qij = *(const float4*)(Jb + (size_t)ri * W + gc);
            Qoi = *(const float4*)(Ib + (size_t)ro * W + gc);
            Qoj = *(const float4*)(Jb + (size_t)ro * W + gc);
        }

        const float rmi = (r + 4 < H)  ? 1.0f : 0.0f;
        const float rmo = (r - 4 >= 0) ? 1.0f : 0.0f;
        float4 vi = Pii, vj = Pij, oi = Poi, oj = Poj;
        F4SCALE(vi, rmi) F4SCALE(vj, rmi) F4SCALE(oi, rmo) F4SCALE(oj, rmo)

        // in-add: cs becomes the 9-row colsum [r-4, r+4]
        F4ADD(cs0, vi) F4ADD(cs1, vj)
        F4FMA(cs2, vi, vi) F4FMA(cs3, vj, vj) F4FMA(cs4, vi, vj)

        // publish own 4 colsums x 5 channels
        const int bu = r & 1;
        *(float4*)&csb[bu][0][4 + gc] = cs0;
        *(float4*)&csb[bu][1][4 + gc] = cs1;
        *(float4*)&csb[bu][2][4 + gc] = cs2;
        *(float4*)&csb[bu][3][4 + gc] = cs3;
        *(float4*)&csb[bu][4][4 + gc] = cs4;
        __syncthreads();

        // horizontal 9-sums: w0..w3 = left neighbor, w4..w7 = own (regs),
        // w8..w11 = right neighbor. out col e = gc + e.
        float hI[4], hJ[4], hII[4], hJJ[4], hIJ[4];
#define HS(ch, M, hh)                                                     \
        {                                                                 \
            const float4 L = *(const float4*)&csb[bu][ch][gc];            \
            const float4 R = *(const float4*)&csb[bu][ch][gc + 8];        \
            float s = L.x + L.y + L.z + L.w                               \
                    + M.x + M.y + M.z + M.w + R.x;                        \
            hh[0] = s;                                                    \
            s += R.y - L.x; hh[1] = s;                                    \
            s += R.z - L.y; hh[2] = s;                                    \
            s += R.w - L.z; hh[3] = s;                                    \
        }
        HS(0, cs0, hI)
        HS(1, cs1, hJ)
        HS(2, cs2, hII)
        HS(3, cs3, hJJ)
        HS(4, cs4, hIJ)
#undef HS

        // out-sub after hsum: cs becomes the 8-row colsum [r-3, r+4]
        F4SUB(cs0, oi) F4SUB(cs1, oj)
        F4FMS(cs2, oi, oi) F4FMS(cs3, oj, oj) F4FMS(cs4, oi, oj)

        // pixel math for the 4 owned output cols
        #pragma unroll
        for (int e = 0; e < 4; ++e) {
            const float u = -hI[e] * INV_WS;
            const float cross = fmaf(u, hJ[e], hIJ[e]);
            const float Ivar  = fmaf(u, hI[e], hII[e]);
            const float Jvar  = fmaf(-hJ[e] * INV_WS, hJ[e], hJJ[e]);
            float prod = Ivar * Jvar;
            float num  = cross * cross;
            if (!(prod > EPS)) { prod = 1.0f; num = 1.0f; }
            float inv_;
            asm("v_rcp_f32 %0, %1" : "=v"(inv_) : "v"(prod + EPS));
            accum += num * inv_;
        }

        Pii = Qii; Pij = Qij; Poi = Qoi; Poj = Qoj;
    }

    // ---- wave reduction + one atomic per wave ----
    #pragma unroll
    for (int off = 32; off > 0; off >>= 1)
        accum += __shfl_xor(accum, off, 64);
    if (lane == 0) atomicAdd(&acc[b], accum);
}

__global__ void finalize_kernel(const float* __restrict__ acc, float* __restrict__ out) {
    if (threadIdx.x < BATCH)
        out[threadIdx.x] = 1.0f - acc[threadIdx.x] * (1.0f / (float)(H * W));
}

extern "C" void kernel_launch(void* const* d_in, const int* in_sizes, int n_in,
                              void* d_out, int out_size, void* d_ws, size_t ws_size,
                              hipStream_t stream) {
    const float* I = (const float*)d_in[0];
    const float* J = (const float*)d_in[1];
    float* out = (float*)d_out;
    float* acc = (float*)d_ws;

    zero_acc_kernel<<<1, 64, 0, stream>>>(acc);

    dim3 grid(NSEG, BATCH);   // 64 x 16 = 1024 blocks = exactly 4/CU resident
    lncc_cs<<<grid, NTHREADS, 0, stream>>>(I, J, acc);

    finalize_kernel<<<1, 64, 0, stream>>>(acc, out);
}